// Round 1
// baseline (171.568 us; speedup 1.0000x reference)
//
#include <hip/hip_runtime.h>
#include <math.h>

#define D_DIM 512   // key dim == value dim == 512 (float4 x 128)
#define MAXK 1024   // max keys per query supported in LDS (actual: 8)

// ---- counting-sort of keys by owning query ------------------------------

__global__ void zero_counts(int* counts, int n) {
    int i = blockIdx.x * blockDim.x + threadIdx.x;
    if (i < n) counts[i] = 0;
}

__global__ void count_keys(const int* __restrict__ tree_idx,
                           int* __restrict__ counts, int m_total) {
    int m = blockIdx.x * blockDim.x + threadIdx.x;
    if (m < m_total) atomicAdd(&counts[tree_idx[m]], 1);
}

// single-block exclusive scan over n_q counts -> offsets[n_q+1], cursor copy
__global__ __launch_bounds__(1024) void scan_counts(const int* __restrict__ counts,
                                                    int* __restrict__ offsets,
                                                    int* __restrict__ cursor,
                                                    int n_q) {
    __shared__ int sh[1024];
    const int tid = threadIdx.x;
    const int items = (n_q + 1023) >> 10;
    const int base_idx = tid * items;

    int local = 0;
    for (int i = 0; i < items; ++i) {
        int idx = base_idx + i;
        if (idx < n_q) local += counts[idx];
    }
    sh[tid] = local;
    __syncthreads();
    // Hillis-Steele inclusive scan over thread sums
    for (int ofs = 1; ofs < 1024; ofs <<= 1) {
        int v = (tid >= ofs) ? sh[tid - ofs] : 0;
        __syncthreads();
        sh[tid] += v;
        __syncthreads();
    }
    int run = (tid == 0) ? 0 : sh[tid - 1];
    for (int i = 0; i < items; ++i) {
        int idx = base_idx + i;
        if (idx < n_q) {
            offsets[idx] = run;
            cursor[idx]  = run;
            run += counts[idx];
        }
    }
    if (tid == 1023) offsets[n_q] = sh[1023];
}

__global__ void scatter_keys(const int* __restrict__ tree_idx,
                             int* __restrict__ cursor,
                             int* __restrict__ keylist, int m_total) {
    int m = blockIdx.x * blockDim.x + threadIdx.x;
    if (m < m_total) {
        int p = atomicAdd(&cursor[tree_idx[m]], 1);
        keylist[p] = m;
    }
}

// ---- main: one wave (64 lanes) per query --------------------------------
// lane owns dims [4*lane .. 4*lane+3] and [4*(lane+64) .. 4*(lane+64)+3]

__global__ __launch_bounds__(64) void attn_segment(
        const float* __restrict__ query, const float* __restrict__ keys,
        const float* __restrict__ values, const int* __restrict__ offsets,
        const int* __restrict__ keylist, float* __restrict__ att,
        float* __restrict__ colsum) {
    const int q    = blockIdx.x;
    const int lane = threadIdx.x;  // 0..63, one wave
    const int off  = offsets[q];
    int nk = offsets[q + 1] - off;
    if (nk > MAXK) nk = MAXK;   // actual workload: nk == 8

    __shared__ float s_sc[MAXK];
    __shared__ int   s_m[MAXK];

    for (int j = lane; j < nk; j += 64) s_m[j] = keylist[off + j];

    const float4* qp = (const float4*)(query + (size_t)q * D_DIM);
    float4 qa = qp[lane];
    float4 qb = qp[lane + 64];
    float pq = qa.x*qa.x + qa.y*qa.y + qa.z*qa.z + qa.w*qa.w
             + qb.x*qb.x + qb.y*qb.y + qb.z*qb.z + qb.w*qb.w;
#pragma unroll
    for (int o = 32; o > 0; o >>= 1) pq += __shfl_down(pq, o);
    pq = __shfl(pq, 0);
    const float qinv = 1.0f / fmaxf(sqrtf(pq), 1e-12f);

    __syncthreads();

    // cosine scores per owned key
    for (int j = 0; j < nk; ++j) {
        const float4* kp = (const float4*)(keys + (size_t)s_m[j] * D_DIM);
        float4 ka = kp[lane];
        float4 kb = kp[lane + 64];
        float pd = qa.x*ka.x + qa.y*ka.y + qa.z*ka.z + qa.w*ka.w
                 + qb.x*kb.x + qb.y*kb.y + qb.z*kb.z + qb.w*kb.w;
        float pk = ka.x*ka.x + ka.y*ka.y + ka.z*ka.z + ka.w*ka.w
                 + kb.x*kb.x + kb.y*kb.y + kb.z*kb.z + kb.w*kb.w;
#pragma unroll
        for (int o = 32; o > 0; o >>= 1) {
            pd += __shfl_down(pd, o);
            pk += __shfl_down(pk, o);
        }
        if (lane == 0) {
            float kinv = 1.0f / fmaxf(sqrtf(pk), 1e-12f);
            s_sc[j] = pd * qinv * kinv;
        }
    }
    __syncthreads();

    // single-wave softmax over nk scores
    float mx = -INFINITY;
    for (int j = lane; j < nk; j += 64) mx = fmaxf(mx, s_sc[j]);
#pragma unroll
    for (int o = 32; o > 0; o >>= 1) mx = fmaxf(mx, __shfl_down(mx, o));
    mx = __shfl(mx, 0);

    float sum = 0.0f;
    for (int j = lane; j < nk; j += 64) {
        float e = __expf(s_sc[j] - mx);
        s_sc[j] = e;
        sum += e;
    }
#pragma unroll
    for (int o = 32; o > 0; o >>= 1) sum += __shfl_down(sum, o);
    sum = __shfl(sum, 0);
    const float inv = (sum > 0.0f) ? 1.0f / sum : 0.0f;

    for (int j = lane; j < nk; j += 64) {
        float a = s_sc[j] * inv;
        s_sc[j] = a;
        colsum[s_m[j]] = a;   // column-sum output: one non-masked entry per column
    }
    __syncthreads();

    // att[q] = sum_j alpha_j * values[m_j]
    float4 acc_a = make_float4(0.f, 0.f, 0.f, 0.f);
    float4 acc_b = make_float4(0.f, 0.f, 0.f, 0.f);
    for (int j = 0; j < nk; ++j) {
        const float a = s_sc[j];
        const float4* vp = (const float4*)(values + (size_t)s_m[j] * D_DIM);
        float4 va = vp[lane];
        float4 vb = vp[lane + 64];
        acc_a.x += a * va.x; acc_a.y += a * va.y; acc_a.z += a * va.z; acc_a.w += a * va.w;
        acc_b.x += a * vb.x; acc_b.y += a * vb.y; acc_b.z += a * vb.z; acc_b.w += a * vb.w;
    }
    float4* op = (float4*)(att + (size_t)q * D_DIM);
    op[lane]      = acc_a;
    op[lane + 64] = acc_b;
}

extern "C" void kernel_launch(void* const* d_in, const int* in_sizes, int n_in,
                              void* d_out, int out_size, void* d_ws, size_t ws_size,
                              hipStream_t stream) {
    const float* query    = (const float*)d_in[0];
    const float* keys     = (const float*)d_in[1];
    const float* values   = (const float*)d_in[2];
    const int*   tree_idx = (const int*)d_in[3];

    const int n_q     = in_sizes[0] / D_DIM;  // 4096
    const int m_total = in_sizes[3];          // 32768

    float* att    = (float*)d_out;
    float* colsum = att + (size_t)n_q * D_DIM;

    // workspace layout (ints): counts[n_q] | offsets[n_q+1] | cursor[n_q] | keylist[m]
    int* counts  = (int*)d_ws;
    int* offsets = counts + n_q;
    int* cursor  = offsets + n_q + 1;
    int* keylist = cursor + n_q;

    zero_counts<<<(n_q + 255) / 256, 256, 0, stream>>>(counts, n_q);
    count_keys<<<(m_total + 255) / 256, 256, 0, stream>>>(tree_idx, counts, m_total);
    scan_counts<<<1, 1024, 0, stream>>>(counts, offsets, cursor, n_q);
    scatter_keys<<<(m_total + 255) / 256, 256, 0, stream>>>(tree_idx, cursor, keylist, m_total);
    attn_segment<<<n_q, 64, 0, stream>>>(query, keys, values, offsets, keylist, att, colsum);
}